// Round 1
// baseline (2500.246 us; speedup 1.0000x reference)
//
#include <hip/hip_runtime.h>
#include <hip/hip_bf16.h>

// Qwen3-MoE forward, MI355X. Router-critical math is fp32-faithful: dense GEMMs
// run on the bf16 MFMA pipe via an EXACT 3-plane bf16 split (x == xh+xm+xl,
// truncation split, 6 cross products -> rel err ~1e-7 < fp32 reorder noise),
// so top-k expert selection matches the fp32 reference as well as the old
// fp32-vector GEMM did. bf16 (single-plane) only for the final logits GEMM.

constexpr int S_ = 2048, D_ = 1024, H_ = 16, HD_ = 64, E_ = 8, MF_ = 768, V_ = 32000;

typedef short  short8 __attribute__((ext_vector_type(8)));
typedef float  f32x4  __attribute__((ext_vector_type(4)));

static __device__ __forceinline__ unsigned short f2bf(float f) {
    unsigned u = __float_as_uint(f);
    u += 0x7FFF + ((u >> 16) & 1);          // RNE
    return (unsigned short)(u >> 16);
}

// ---------------- embed gather ----------------
__global__ __launch_bounds__(256) void k_gather(const int* __restrict__ ids,
                                                const float* __restrict__ emb,
                                                float* __restrict__ h) {
    int tok = blockIdx.x;
    int id  = ids[tok];
    const float4* src = (const float4*)(emb + (long)id * D_);
    float4*       dst = (float4*)(h + (long)tok * D_);
    dst[threadIdx.x] = src[threadIdx.x];
}

// ---------------- rmsnorm (row per block) ----------------
template <int BF>
__global__ __launch_bounds__(256) void k_rmsnorm(const float* __restrict__ in,
                                                 const float* __restrict__ w,
                                                 float* __restrict__ outf,
                                                 unsigned short* __restrict__ outb) {
    int row = blockIdx.x, t = threadIdx.x;
    float4 x = ((const float4*)(in + (long)row * D_))[t];
    float ss = x.x * x.x + x.y * x.y + x.z * x.z + x.w * x.w;
#pragma unroll
    for (int m = 32; m >= 1; m >>= 1) ss += __shfl_xor(ss, m);
    __shared__ float ps[4];
    if ((t & 63) == 0) ps[t >> 6] = ss;
    __syncthreads();
    float tot   = ps[0] + ps[1] + ps[2] + ps[3];
    float scale = 1.0f / sqrtf(tot * (1.0f / D_) + 1e-6f);
    float4 wv = ((const float4*)w)[t];
    float4 o;
    o.x = x.x * scale * wv.x; o.y = x.y * scale * wv.y;
    o.z = x.z * scale * wv.z; o.w = x.w * scale * wv.w;
    if (BF) {
        ushort4 ub;
        ub.x = f2bf(o.x); ub.y = f2bf(o.y); ub.z = f2bf(o.z); ub.w = f2bf(o.w);
        *(ushort4*)(outb + (long)row * D_ + t * 4) = ub;
    } else {
        ((float4*)(outf + (long)row * D_))[t] = o;
    }
}

// ---------------- per-head RMSNorm + RoPE (one wave per (tensor,tok,head)) ----
__global__ __launch_bounds__(256) void k_qkrope(float* __restrict__ q, float* __restrict__ k,
                                                const float* __restrict__ qn,
                                                const float* __restrict__ kn,
                                                const float* __restrict__ cosb,
                                                const float* __restrict__ sinb) {
    int wid  = (blockIdx.x << 2) | (threadIdx.x >> 6);   // 0 .. 65535
    int lane = threadIdx.x & 63;
    int tensor = wid >> 15;
    int rem    = wid & 32767;
    int tok = rem >> 4, head = rem & 15;
    float* ptr = tensor ? k : q;
    const float* nw = tensor ? kn : qn;
    long off = ((long)tok * H_ + head) * HD_ + lane;
    float v = ptr[off];
    float ss = v * v;
#pragma unroll
    for (int m = 32; m >= 1; m >>= 1) ss += __shfl_xor(ss, m);
    float xn = v * (1.0f / sqrtf(ss * (1.0f / HD_) + 1e-6f)) * nw[lane];
    float other = __shfl_xor(xn, 32);
    float rot = (lane < 32) ? -other : other;
    ptr[off] = xn * cosb[tok * HD_ + lane] + rot * sinb[tok * HD_ + lane];
}

// ---------------- exact 3-plane bf16 split helpers ----------------
// Truncation split: x = xh + xm + xl EXACTLY (8+8+8 significand bits).
// Packs two elements into one u32 per plane (lo short = elem0, hi = elem1).
static __device__ __forceinline__ void splitpack2(float x0, float x1,
                                                  unsigned& wh, unsigned& wm,
                                                  unsigned& wl) {
    unsigned u0 = __float_as_uint(x0), u1 = __float_as_uint(x1);
    unsigned h0 = u0 & 0xFFFF0000u,    h1 = u1 & 0xFFFF0000u;
    float r0 = x0 - __uint_as_float(h0), r1 = x1 - __uint_as_float(h1);
    unsigned m0 = __float_as_uint(r0) & 0xFFFF0000u;
    unsigned m1 = __float_as_uint(r1) & 0xFFFF0000u;
    float s0 = r0 - __uint_as_float(m0), s1 = r1 - __uint_as_float(m1);
    unsigned l0 = __float_as_uint(s0),   l1 = __float_as_uint(s1);
    wh = (h0 >> 16) | h1;
    wm = (m0 >> 16) | m1;
    wl = (l0 >> 16) | (l1 & 0xFFFF0000u);
}

static __device__ __forceinline__ void split8(const float* v,
                                              uint4& qh, uint4& qm, uint4& ql) {
    unsigned ph[4], pm[4], pl[4];
#pragma unroll
    for (int j = 0; j < 4; j++) splitpack2(v[2 * j], v[2 * j + 1], ph[j], pm[j], pl[j]);
    qh = make_uint4(ph[0], ph[1], ph[2], ph[3]);
    qm = make_uint4(pm[0], pm[1], pm[2], pm[3]);
    ql = make_uint4(pl[0], pl[1], pl[2], pl[3]);
}

// ---------------- split-bf16 MFMA GEMM: C[M,N] = A[M,K] @ B[K,N] ----------------
// fp32-faithful via 6 products: ah*bh + ah*bm + am*bh + ah*bl + am*bm + al*bh.
// A is fp32 row-major [m][k] (K-contig, split in regs during staging).
// B is fp32 row-major [k][n]; staged transposed into LDS planes [n][k].
// IND: A rows indirected via rows[]. EPI: 0 store, 1 in-place residual add,
//      2 scaled atomic scatter into hout.
// z-dim: if B1 != null, z in {0,1,2} selects B0/B1/B2 (fused QKV, C stride cStrideZ);
//        else Bz = B0 + z*bStrideZ (MoE experts).
template <int IND, int EPI>
__global__ __launch_bounds__(256) void k_gemm_s6(const float* __restrict__ A,
                                                 const float* __restrict__ B0,
                                                 const float* __restrict__ B1,
                                                 const float* __restrict__ B2,
                                                 float* __restrict__ C,
                                                 const int* __restrict__ offs,
                                                 const int* __restrict__ rows,
                                                 const float* __restrict__ rwgt,
                                                 float* __restrict__ hout,
                                                 int Mtot, int N, int K,
                                                 long bStrideZ, long cStrideZ) {
    int z = blockIdx.z;
    int ms, me;
    if (offs) { ms = offs[z]; me = offs[z + 1]; }
    else      { ms = 0; me = Mtot; }
    int p0 = ms + blockIdx.y * 128;
    if (p0 >= me) return;
    const float* Bz;
    if (B1) Bz = (z == 0) ? B0 : (z == 1) ? B1 : B2;
    else    Bz = B0 + (long)z * bStrideZ;
    float* Cz = C ? (C + (long)z * cStrideZ) : nullptr;
    int n0 = blockIdx.x * 128;

    __shared__ __align__(16) unsigned short As[3][128][40];  // planes h/m/l, [m][k]
    __shared__ __align__(16) unsigned short Bs[3][128][40];  // planes h/m/l, [n][k]

    int t = threadIdx.x;
    int lane = t & 63, wave = t >> 6;
    int wm = (wave >> 1) * 64, wn = (wave & 1) * 64;
    int ln = lane & 15, lq = lane >> 4;

    f32x4 acc[4][4];
    f32x4 zero4 = {0.f, 0.f, 0.f, 0.f};
#pragma unroll
    for (int r = 0; r < 4; r++)
#pragma unroll
        for (int c = 0; c < 4; c++) acc[r][c] = zero4;

    int arow = t >> 1, ak0 = (t & 1) * 16;   // A: row, k-half of 32
    const float* aptr = nullptr;
    {
        int pA = p0 + arow;
        if (pA < me) {
            int srow = IND ? rows[pA] : pA;
            aptr = A + (long)srow * K + ak0;
        }
    }
    // B: thread owns one n (t>>1) and one k-half; loads 16 strided dwords.
    int brow = t >> 1, bk0 = (t & 1) * 16;
    const float* bbase = Bz + (n0 + brow);

    for (int k0 = 0; k0 < K; k0 += 32) {
        // ---- load + split A (16 elems -> 3 planes x 2 uint4)
        float va[16];
        if (aptr) {
#pragma unroll
            for (int c4 = 0; c4 < 4; c4++) {
                float4 f = *(const float4*)(aptr + k0 + c4 * 4);
                va[c4 * 4 + 0] = f.x; va[c4 * 4 + 1] = f.y;
                va[c4 * 4 + 2] = f.z; va[c4 * 4 + 3] = f.w;
            }
        } else {
#pragma unroll
            for (int j = 0; j < 16; j++) va[j] = 0.f;
        }
        uint4 ah0, am0, al0, ah1, am1, al1;
        split8(va,     ah0, am0, al0);
        split8(va + 8, ah1, am1, al1);
        // ---- load + split B (16 strided dwords along k at fixed n)
        float vb[16];
        {
            const float* bp = bbase + (long)(k0 + bk0) * N;
#pragma unroll
            for (int j = 0; j < 16; j++) vb[j] = bp[(long)j * N];
        }
        uint4 bh0, bm0, bl0, bh1, bm1, bl1;
        split8(vb,     bh0, bm0, bl0);
        split8(vb + 8, bh1, bm1, bl1);

        __syncthreads();   // previous tile fully consumed
        *(uint4*)&As[0][arow][ak0]     = ah0;
        *(uint4*)&As[0][arow][ak0 + 8] = ah1;
        *(uint4*)&As[1][arow][ak0]     = am0;
        *(uint4*)&As[1][arow][ak0 + 8] = am1;
        *(uint4*)&As[2][arow][ak0]     = al0;
        *(uint4*)&As[2][arow][ak0 + 8] = al1;
        *(uint4*)&Bs[0][brow][bk0]     = bh0;
        *(uint4*)&Bs[0][brow][bk0 + 8] = bh1;
        *(uint4*)&Bs[1][brow][bk0]     = bm0;
        *(uint4*)&Bs[1][brow][bk0 + 8] = bm1;
        *(uint4*)&Bs[2][brow][bk0]     = bl0;
        *(uint4*)&Bs[2][brow][bk0 + 8] = bl1;
        __syncthreads();

        short8 fah[4], fam[4], fal[4];
#pragma unroll
        for (int r = 0; r < 4; r++) {
            fah[r] = *(const short8*)&As[0][wm + 16 * r + ln][lq * 8];
            fam[r] = *(const short8*)&As[1][wm + 16 * r + ln][lq * 8];
            fal[r] = *(const short8*)&As[2][wm + 16 * r + ln][lq * 8];
        }
#pragma unroll
        for (int c = 0; c < 4; c++) {
            short8 fbh = *(const short8*)&Bs[0][wn + 16 * c + ln][lq * 8];
            short8 fbm = *(const short8*)&Bs[1][wn + 16 * c + ln][lq * 8];
            short8 fbl = *(const short8*)&Bs[2][wn + 16 * c + ln][lq * 8];
#pragma unroll
            for (int r = 0; r < 4; r++) {
                f32x4 a2 = acc[r][c];
                a2 = __builtin_amdgcn_mfma_f32_16x16x32_bf16(fah[r], fbh, a2, 0, 0, 0);
                a2 = __builtin_amdgcn_mfma_f32_16x16x32_bf16(fah[r], fbm, a2, 0, 0, 0);
                a2 = __builtin_amdgcn_mfma_f32_16x16x32_bf16(fam[r], fbh, a2, 0, 0, 0);
                a2 = __builtin_amdgcn_mfma_f32_16x16x32_bf16(fah[r], fbl, a2, 0, 0, 0);
                a2 = __builtin_amdgcn_mfma_f32_16x16x32_bf16(fam[r], fbm, a2, 0, 0, 0);
                a2 = __builtin_amdgcn_mfma_f32_16x16x32_bf16(fal[r], fbh, a2, 0, 0, 0);
                acc[r][c] = a2;
            }
        }
    }

    // C/D: col=lane&15, row=(lane>>4)*4+i  [m89-verified]
#pragma unroll
    for (int r = 0; r < 4; r++)
#pragma unroll
        for (int c = 0; c < 4; c++) {
            int rowb = wm + 16 * r + lq * 4;
            int col  = n0 + wn + 16 * c + ln;
#pragma unroll
            for (int i = 0; i < 4; i++) {
                int p = p0 + rowb + i;
                if (p >= me) continue;
                if (EPI == 2) {
                    atomicAdd(hout + (long)rows[p] * N + col, rwgt[p] * acc[r][c][i]);
                } else if (EPI == 1) {
                    float* cp = Cz + (long)p * N + col;
                    *cp += acc[r][c][i];
                } else {
                    Cz[(long)p * N + col] = acc[r][c][i];
                }
            }
        }
}

// ---------------- fp32 flash attention, 32-row Q tile per block ----------------
__global__ __launch_bounds__(256) void k_attn(const float* __restrict__ q,
                                              const float* __restrict__ k,
                                              const float* __restrict__ v,
                                              float* __restrict__ o) {
    int head = blockIdx.y;
    int q0   = blockIdx.x * 32;
    __shared__ __align__(16) float Qs[32][68];
    __shared__ __align__(16) float Kt[64][68];   // transposed: Kt[d][col]
    __shared__ __align__(16) float Vs[64][68];
    __shared__ __align__(16) float Ss[32][68];
    __shared__ float red[32][8];
    __shared__ float mrow[32], lrow[32], arow[32];
    int t = threadIdx.x;
    int r = t >> 3, c0 = (t & 7) * 8;
    float o8[8] = {0.f, 0.f, 0.f, 0.f, 0.f, 0.f, 0.f, 0.f};
    {
        int qr = t >> 3, d0 = (t & 7) * 8;
        const float* qp = q + ((long)(q0 + qr) * H_ + head) * HD_ + d0;
        *(float4*)&Qs[qr][d0]     = *(const float4*)qp;
        *(float4*)&Qs[qr][d0 + 4] = *(const float4*)(qp + 4);
    }
    if (t < 32) { mrow[t] = -3.402823466e38f; lrow[t] = 0.f; }
    int ktmax = (q0 + 31) >> 6;
    for (int kt = 0; kt <= ktmax; kt++) {
        __syncthreads();
        {
            int row = t >> 2, d0 = (t & 3) * 16;
            const float* kp = k + ((long)(kt * 64 + row) * H_ + head) * HD_ + d0;
            const float* vp = v + ((long)(kt * 64 + row) * H_ + head) * HD_ + d0;
#pragma unroll
            for (int j = 0; j < 4; j++) {
                float4 kv = *(const float4*)(kp + 4 * j);
                float4 vv = *(const float4*)(vp + 4 * j);
                *(float4*)&Vs[row][d0 + 4 * j] = vv;
                Kt[d0 + 4 * j + 0][row] = kv.x;
                Kt[d0 + 4 * j + 1][row] = kv.y;
                Kt[d0 + 4 * j + 2][row] = kv.z;
                Kt[d0 + 4 * j + 3][row] = kv.w;
            }
        }
        __syncthreads();
        float s8[8] = {0.f, 0.f, 0.f, 0.f, 0.f, 0.f, 0.f, 0.f};
#pragma unroll 8
        for (int d = 0; d < 64; d++) {
            float qv = Qs[r][d];
            float4 ka = *(const float4*)&Kt[d][c0];
            float4 kb = *(const float4*)&Kt[d][c0 + 4];
            s8[0] = fmaf(qv, ka.x, s8[0]); s8[1] = fmaf(qv, ka.y, s8[1]);
            s8[2] = fmaf(qv, ka.z, s8[2]); s8[3] = fmaf(qv, ka.w, s8[3]);
            s8[4] = fmaf(qv, kb.x, s8[4]); s8[5] = fmaf(qv, kb.y, s8[5]);
            s8[6] = fmaf(qv, kb.z, s8[6]); s8[7] = fmaf(qv, kb.w, s8[7]);
        }
        int qrow = q0 + r;
        float mx = -3.402823466e38f;
#pragma unroll
        for (int j = 0; j < 8; j++) {
            int col = kt * 64 + c0 + j;
            s8[j] = (col <= qrow) ? s8[j] * 0.125f : -3.402823466e38f;
            mx = fmaxf(mx, s8[j]);
        }
        red[r][t & 7] = mx;
        __syncthreads();
        if (t < 32) {
            float m0 = mrow[t];
            float mt = red[t][0];
#pragma unroll
            for (int j = 1; j < 8; j++) mt = fmaxf(mt, red[t][j]);
            float mn = fmaxf(m0, mt);
            mrow[t] = mn;
            arow[t] = expf(m0 - mn);
        }
        __syncthreads();
        float mn = mrow[r], al = arow[r];
        float sum = 0.f;
#pragma unroll
        for (int j = 0; j < 8; j++) {
            float e = expf(s8[j] - mn);
            s8[j] = e; sum += e;
        }
        red[r][t & 7] = sum;
        *(float4*)&Ss[r][c0]     = make_float4(s8[0], s8[1], s8[2], s8[3]);
        *(float4*)&Ss[r][c0 + 4] = make_float4(s8[4], s8[5], s8[6], s8[7]);
#pragma unroll
        for (int j = 0; j < 8; j++) o8[j] *= al;
        __syncthreads();
        if (t < 32) {
            float su = red[t][0] + red[t][1] + red[t][2] + red[t][3] +
                       red[t][4] + red[t][5] + red[t][6] + red[t][7];
            lrow[t] = lrow[t] * arow[t] + su;
        }
#pragma unroll 8
        for (int kk2 = 0; kk2 < 64; kk2++) {
            float p = Ss[r][kk2];
            float4 va = *(const float4*)&Vs[kk2][c0];
            float4 vb = *(const float4*)&Vs[kk2][c0 + 4];
            o8[0] = fmaf(p, va.x, o8[0]); o8[1] = fmaf(p, va.y, o8[1]);
            o8[2] = fmaf(p, va.z, o8[2]); o8[3] = fmaf(p, va.w, o8[3]);
            o8[4] = fmaf(p, vb.x, o8[4]); o8[5] = fmaf(p, vb.y, o8[5]);
            o8[6] = fmaf(p, vb.w * 0.f + vb.z, o8[6]); o8[7] = fmaf(p, vb.w, o8[7]);
        }
    }
    __syncthreads();
    float invl = 1.0f / lrow[r];
    float* op = o + ((long)(q0 + r) * H_ + head) * HD_ + c0;
    *(float4*)op       = make_float4(o8[0] * invl, o8[1] * invl, o8[2] * invl, o8[3] * invl);
    *(float4*)(op + 4) = make_float4(o8[4] * invl, o8[5] * invl, o8[6] * invl, o8[7] * invl);
}

// ---------------- router: gate logits, softmax-top2 (stable), counts --------
__global__ __launch_bounds__(256) void k_router(const float* __restrict__ x,
                                                const float* __restrict__ gw,
                                                int* __restrict__ idx, float* __restrict__ wgt,
                                                int* __restrict__ cnt) {
    int tok  = (blockIdx.x << 2) | (threadIdx.x >> 6);
    int lane = threadIdx.x & 63;
    float acc[8] = {0.f, 0.f, 0.f, 0.f, 0.f, 0.f, 0.f, 0.f};
    for (int i = 0; i < 16; i++) {
        int d = lane + i * 64;
        float xv = x[(long)tok * D_ + d];
        const float* gp = gw + (long)d * E_;
#pragma unroll
        for (int e = 0; e < 8; e++) acc[e] = fmaf(xv, gp[e], acc[e]);
    }
#pragma unroll
    for (int e = 0; e < 8; e++)
#pragma unroll
        for (int m = 32; m >= 1; m >>= 1) acc[e] += __shfl_xor(acc[e], m);
    if (lane == 0) {
        int i1 = 0; float m1 = acc[0];
        for (int e = 1; e < 8; e++) if (acc[e] > m1) { m1 = acc[e]; i1 = e; }
        int i2 = -1; float m2 = -3.402823466e38f;
        for (int e = 0; e < 8; e++) if (e != i1 && acc[e] > m2) { m2 = acc[e]; i2 = e; }
        float w1 = 1.0f / (1.0f + expf(m2 - m1));
        idx[tok * 2] = i1; idx[tok * 2 + 1] = i2;
        wgt[tok * 2] = w1; wgt[tok * 2 + 1] = 1.0f - w1;
        atomicAdd(&cnt[i1], 1);
        atomicAdd(&cnt[i2], 1);
    }
}

__global__ void k_offsets(const int* __restrict__ cnt, int* __restrict__ off) {
    if (threadIdx.x == 0) {
        int run = 0;
        for (int e = 0; e < 8; e++) { off[e] = run; run += cnt[e]; }
        off[8] = run;
    }
}

__global__ __launch_bounds__(256) void k_scatter(const int* __restrict__ idx,
                                                 const float* __restrict__ wgt,
                                                 const int* __restrict__ off,
                                                 int* __restrict__ fill,
                                                 int* __restrict__ rows,
                                                 float* __restrict__ rwgt) {
    int tok = blockIdx.x * 256 + threadIdx.x;
#pragma unroll
    for (int j = 0; j < 2; j++) {
        int e = idx[tok * 2 + j];
        int pos = off[e] + atomicAdd(&fill[e], 1);
        rows[pos] = tok;
        rwgt[pos] = wgt[tok * 2 + j];
    }
}

__global__ __launch_bounds__(256) void k_silumul(const float* __restrict__ g,
                                                 const float* __restrict__ u,
                                                 float* __restrict__ z) {
    long i = (long)(blockIdx.x * 256 + threadIdx.x) * 4;
    float4 gv = *(const float4*)(g + i);
    float4 uv = *(const float4*)(u + i);
    float4 zv;
    zv.x = gv.x / (1.f + expf(-gv.x)) * uv.x;
    zv.y = gv.y / (1.f + expf(-gv.y)) * uv.y;
    zv.z = gv.z / (1.f + expf(-gv.z)) * uv.z;
    zv.w = gv.w / (1.f + expf(-gv.w)) * uv.w;
    *(float4*)(z + i) = zv;
}

// ---------------- transpose + cast: out_w (1024,32000) f32 -> (32000,1024) bf16
__global__ __launch_bounds__(256) void k_transcast(const float* __restrict__ in,
                                                   unsigned short* __restrict__ out) {
    int c0 = blockIdx.x * 32;   // n
    int r0 = blockIdx.y * 32;   // k
    __shared__ __align__(16) float T[32][36];
    int t = threadIdx.x;
    {
        int row = t >> 3, cq = (t & 7) * 4;
        *(float4*)&T[row][cq] = *(const float4*)(in + (long)(r0 + row) * V_ + c0 + cq);
    }
    __syncthreads();
    {
        int n = t >> 3, kq = (t & 7) * 4;
        ushort4 u;
        u.x = f2bf(T[kq + 0][n]); u.y = f2bf(T[kq + 1][n]);
        u.z = f2bf(T[kq + 2][n]); u.w = f2bf(T[kq + 3][n]);
        *(ushort4*)(out + (long)(c0 + n) * D_ + r0 + kq) = u;
    }
}

// ---------------- bf16 MFMA GEMM for logits: C = A(2048,1024) @ BT(32000,1024)^T
__global__ __launch_bounds__(256) void k_gemm_bf16(const unsigned short* __restrict__ A,
                                                   const unsigned short* __restrict__ BT,
                                                   float* __restrict__ C) {
    int m0 = blockIdx.x * 128, n0 = blockIdx.y * 128;
    __shared__ __align__(16) unsigned short As[128][40];  // stride 40 shorts = 80B (conflict-clean frag reads)
    __shared__ __align__(16) unsigned short Bs[128][40];
    int t = threadIdx.x;
    int lane = t & 63, wave = t >> 6;
    int wm = (wave >> 1) * 64, wn = (wave & 1) * 64;
    int ln = lane & 15, lq = lane >> 4;
    f32x4 acc[4][4];
    f32x4 zero4 = {0.f, 0.f, 0.f, 0.f};
#pragma unroll
    for (int r = 0; r < 4; r++)
#pragma unroll
        for (int c = 0; c < 4; c++) acc[r][c] = zero4;
    int rowA = t >> 1;
    int q1 = (t * 2) & 3, q2 = (t * 2 + 1) & 3;
    for (int k0 = 0; k0 < 1024; k0 += 32) {
        const uint4* ap = (const uint4*)(A + (long)(m0 + rowA) * 1024 + k0);
        const uint4* bp = (const uint4*)(BT + (long)(n0 + rowA) * 1024 + k0);
        uint4 a0 = ap[q1], a1 = ap[q2];
        uint4 b0 = bp[q1], b1 = bp[q2];
        __syncthreads();
        *(uint4*)&As[rowA][q1 * 8] = a0;
        *(uint4*)&As[rowA][q2 * 8] = a1;
        *(uint4*)&Bs[rowA][q1 * 8] = b0;
        *(uint4*)&Bs[rowA][q2 * 8] = b1;
        __syncthreads();
        short8 a[4], b[4];
#pragma unroll
        for (int r = 0; r < 4; r++) a[r] = *(const short8*)&As[wm + 16 * r + ln][lq * 8];
#pragma unroll
        for (int c = 0; c < 4; c++) b[c] = *(const short8*)&Bs[wn + 16 * c + ln][lq * 8];
#pragma unroll
        for (int r = 0; r < 4; r++)
#pragma unroll
            for (int c = 0; c < 4; c++)
                acc[r][c] = __builtin_amdgcn_mfma_f32_16x16x32_bf16(a[r], b[c], acc[r][c], 0, 0, 0);
    }
#pragma unroll
    for (int r = 0; r < 4; r++)
#pragma unroll
        for (int c = 0; c < 4; c++) {
            int row = m0 + wm + 16 * r + lq * 4;   // C/D: col=lane&15, row=(lane>>4)*4+i  [m89-verified]
            int col = n0 + wn + 16 * c + ln;
#pragma unroll
            for (int i = 0; i < 4; i++)
                C[(long)(row + i) * V_ + col] = acc[r][c][i];
        }
}

// ---------------- host ----------------
extern "C" void kernel_launch(void* const* d_in, const int* in_sizes, int n_in,
                              void* d_out, int out_size, void* d_ws, size_t ws_size,
                              hipStream_t stream) {
    (void)in_sizes; (void)n_in; (void)out_size; (void)ws_size;
    const int*   ids   = (const int*)d_in[0];
    const float* embed = (const float*)d_in[1];
    const float* wq    = (const float*)d_in[2];
    const float* wk    = (const float*)d_in[3];
    const float* wv    = (const float*)d_in[4];
    const float* wo    = (const float*)d_in[5];
    const float* qnw   = (const float*)d_in[6];
    const float* knw   = (const float*)d_in[7];
    const float* anw   = (const float*)d_in[8];
    const float* fnw   = (const float*)d_in[9];
    const float* gatew = (const float*)d_in[10];
    const float* wgate = (const float*)d_in[11];
    const float* wup   = (const float*)d_in[12];
    const float* wdown = (const float*)d_in[13];
    const float* finw  = (const float*)d_in[14];
    const float* outw  = (const float*)d_in[15];
    const float* cosb  = (const float*)d_in[16];
    const float* sinb  = (const float*)d_in[17];
    float* out = (float*)d_out;

    char* w = (char*)d_ws;
    float* h  = (float*)(w);
    float* x  = (float*)(w + 8388608);
    float* q  = (float*)(w + 16777216);
    float* kk = (float*)(w + 25165824);
    float* vv = (float*)(w + 33554432);
    float* ao = (float*)(w + 41943040);
    float* g  = (float*)(w + 50331648);
    float* u  = (float*)(w + 62914560);
    float* z  = (float*)(w + 75497472);
    unsigned short* hn  = (unsigned short*)(w + 88080384);
    unsigned short* owT = (unsigned short*)(w + 16777216);  // overlays q..z (dead by then)
    char* rbase = w + 92274688;
    int*   idx  = (int*)(rbase);
    float* wgt  = (float*)(rbase + 16384);
    int*   cnt  = (int*)(rbase + 32768);
    int*   fill = (int*)(rbase + 32768 + 32);
    int*   offs = (int*)(rbase + 32768 + 64);
    int*   rows = (int*)(rbase + 32768 + 128);
    float* rwgt = (float*)(rbase + 32768 + 128 + 16384);

    k_gather<<<2048, 256, 0, stream>>>(ids, embed, h);

    for (int l = 0; l < 2; l++) {
        const float* wq_l = wq + (long)l * D_ * D_;
        const float* wk_l = wk + (long)l * D_ * D_;
        const float* wv_l = wv + (long)l * D_ * D_;
        const float* wo_l = wo + (long)l * D_ * D_;
        const float* an_l = anw + l * D_;
        const float* fn_l = fnw + l * D_;
        const float* qn_l = qnw + l * HD_;
        const float* kn_l = knw + l * HD_;
        const float* gw_l = gatew + (long)l * D_ * E_;
        const float* wg_l = wgate + (long)l * E_ * D_ * MF_;
        const float* wu_l = wup   + (long)l * E_ * D_ * MF_;
        const float* wd_l = wdown + (long)l * E_ * MF_ * D_;

        k_rmsnorm<0><<<2048, 256, 0, stream>>>(h, an_l, x, nullptr);
        // fused QKV: z in {0,1,2} selects wq/wk/wv; C = q + z*2M floats (q,kk,vv adjacent)
        k_gemm_s6<0, 0><<<dim3(8, 16, 3), 256, 0, stream>>>(x, wq_l, wk_l, wv_l, q,
            nullptr, nullptr, nullptr, nullptr, 2048, 1024, 1024, 0, 2048L * 1024);
        k_qkrope<<<16384, 256, 0, stream>>>(q, kk, qn_l, kn_l, cosb, sinb);
        k_attn<<<dim3(64, 16), 256, 0, stream>>>(q, kk, vv, ao);
        k_gemm_s6<0, 1><<<dim3(8, 16, 1), 256, 0, stream>>>(ao, wo_l, nullptr, nullptr, h,
            nullptr, nullptr, nullptr, nullptr, 2048, 1024, 1024, 0, 0);
        k_rmsnorm<0><<<2048, 256, 0, stream>>>(h, fn_l, x, nullptr);
        hipMemsetAsync(cnt, 0, 64, stream);
        k_router<<<512, 256, 0, stream>>>(x, gw_l, idx, wgt, cnt);
        k_offsets<<<1, 64, 0, stream>>>(cnt, offs);
        k_scatter<<<8, 256, 0, stream>>>(idx, wgt, offs, fill, rows, rwgt);
        k_gemm_s6<1, 0><<<dim3(6, 16, 8), 256, 0, stream>>>(x, wg_l, nullptr, nullptr, g,
            offs, rows, nullptr, nullptr, 4096, 768, 1024, (long)D_ * MF_, 0);
        k_gemm_s6<1, 0><<<dim3(6, 16, 8), 256, 0, stream>>>(x, wu_l, nullptr, nullptr, u,
            offs, rows, nullptr, nullptr, 4096, 768, 1024, (long)D_ * MF_, 0);
        k_silumul<<<3072, 256, 0, stream>>>(g, u, z);
        k_gemm_s6<0, 2><<<dim3(8, 16, 8), 256, 0, stream>>>(z, wd_l, nullptr, nullptr, nullptr,
            offs, rows, rwgt, h, 4096, 1024, 768, (long)MF_ * D_, 0);
    }

    k_rmsnorm<1><<<2048, 256, 0, stream>>>(h, finw, nullptr, hn);
    k_transcast<<<dim3(1000, 32), 256, 0, stream>>>(outw, owT);
    k_gemm_bf16<<<dim3(16, 250), 256, 0, stream>>>(hn, owT, out);
}

// Round 2
// 2130.602 us; speedup vs baseline: 1.1735x; 1.1735x over previous
//
#include <hip/hip_runtime.h>
#include <hip/hip_bf16.h>

// Qwen3-MoE forward, MI355X. Router-critical math is fp32-faithful: dense GEMMs
// AND attention run on the bf16 MFMA pipe via an EXACT 3-plane bf16 split
// (x == xh+xm+xl, truncation split, 6 cross products -> rel err ~1e-7 <
// fp32 reorder noise), so top-k expert selection matches the fp32 reference.
// bf16 (single-plane) only for the final logits GEMM.

constexpr int S_ = 2048, D_ = 1024, H_ = 16, HD_ = 64, E_ = 8, MF_ = 768, V_ = 32000;

typedef short  short8 __attribute__((ext_vector_type(8)));
typedef float  f32x4  __attribute__((ext_vector_type(4)));

static __device__ __forceinline__ unsigned short f2bf(float f) {
    unsigned u = __float_as_uint(f);
    u += 0x7FFF + ((u >> 16) & 1);          // RNE
    return (unsigned short)(u >> 16);
}

static __device__ __forceinline__ short8 u2s8(uint4 u) {
    union { uint4 a; short8 b; } x; x.a = u; return x.b;
}

// ---------------- embed gather ----------------
__global__ __launch_bounds__(256) void k_gather(const int* __restrict__ ids,
                                                const float* __restrict__ emb,
                                                float* __restrict__ h) {
    int tok = blockIdx.x;
    int id  = ids[tok];
    const float4* src = (const float4*)(emb + (long)id * D_);
    float4*       dst = (float4*)(h + (long)tok * D_);
    dst[threadIdx.x] = src[threadIdx.x];
}

// ---------------- rmsnorm (row per block) ----------------
template <int BF>
__global__ __launch_bounds__(256) void k_rmsnorm(const float* __restrict__ in,
                                                 const float* __restrict__ w,
                                                 float* __restrict__ outf,
                                                 unsigned short* __restrict__ outb) {
    int row = blockIdx.x, t = threadIdx.x;
    float4 x = ((const float4*)(in + (long)row * D_))[t];
    float ss = x.x * x.x + x.y * x.y + x.z * x.z + x.w * x.w;
#pragma unroll
    for (int m = 32; m >= 1; m >>= 1) ss += __shfl_xor(ss, m);
    __shared__ float ps[4];
    if ((t & 63) == 0) ps[t >> 6] = ss;
    __syncthreads();
    float tot   = ps[0] + ps[1] + ps[2] + ps[3];
    float scale = 1.0f / sqrtf(tot * (1.0f / D_) + 1e-6f);
    float4 wv = ((const float4*)w)[t];
    float4 o;
    o.x = x.x * scale * wv.x; o.y = x.y * scale * wv.y;
    o.z = x.z * scale * wv.z; o.w = x.w * scale * wv.w;
    if (BF) {
        ushort4 ub;
        ub.x = f2bf(o.x); ub.y = f2bf(o.y); ub.z = f2bf(o.z); ub.w = f2bf(o.w);
        *(ushort4*)(outb + (long)row * D_ + t * 4) = ub;
    } else {
        ((float4*)(outf + (long)row * D_))[t] = o;
    }
}

// ---------------- per-head RMSNorm + RoPE (one wave per (tensor,tok,head)) ----
__global__ __launch_bounds__(256) void k_qkrope(float* __restrict__ q, float* __restrict__ k,
                                                const float* __restrict__ qn,
                                                const float* __restrict__ kn,
                                                const float* __restrict__ cosb,
                                                const float* __restrict__ sinb) {
    int wid  = (blockIdx.x << 2) | (threadIdx.x >> 6);   // 0 .. 65535
    int lane = threadIdx.x & 63;
    int tensor = wid >> 15;
    int rem    = wid & 32767;
    int tok = rem >> 4, head = rem & 15;
    float* ptr = tensor ? k : q;
    const float* nw = tensor ? kn : qn;
    long off = ((long)tok * H_ + head) * HD_ + lane;
    float v = ptr[off];
    float ss = v * v;
#pragma unroll
    for (int m = 32; m >= 1; m >>= 1) ss += __shfl_xor(ss, m);
    float xn = v * (1.0f / sqrtf(ss * (1.0f / HD_) + 1e-6f)) * nw[lane];
    float other = __shfl_xor(xn, 32);
    float rot = (lane < 32) ? -other : other;
    ptr[off] = xn * cosb[tok * HD_ + lane] + rot * sinb[tok * HD_ + lane];
}

// ---------------- exact 3-plane bf16 split helpers ----------------
// Truncation split: x = xh + xm + xl EXACTLY (8+8+8 significand bits).
// Packs two elements into one u32 per plane (lo short = elem0, hi = elem1).
static __device__ __forceinline__ void splitpack2(float x0, float x1,
                                                  unsigned& wh, unsigned& wm,
                                                  unsigned& wl) {
    unsigned u0 = __float_as_uint(x0), u1 = __float_as_uint(x1);
    unsigned h0 = u0 & 0xFFFF0000u,    h1 = u1 & 0xFFFF0000u;
    float r0 = x0 - __uint_as_float(h0), r1 = x1 - __uint_as_float(h1);
    unsigned m0 = __float_as_uint(r0) & 0xFFFF0000u;
    unsigned m1 = __float_as_uint(r1) & 0xFFFF0000u;
    float s0 = r0 - __uint_as_float(m0), s1 = r1 - __uint_as_float(m1);
    unsigned l0 = __float_as_uint(s0),   l1 = __float_as_uint(s1);
    wh = (h0 >> 16) | h1;
    wm = (m0 >> 16) | m1;
    wl = (l0 >> 16) | (l1 & 0xFFFF0000u);
}

static __device__ __forceinline__ void split8(const float* v,
                                              uint4& qh, uint4& qm, uint4& ql) {
    unsigned ph[4], pm[4], pl[4];
#pragma unroll
    for (int j = 0; j < 4; j++) splitpack2(v[2 * j], v[2 * j + 1], ph[j], pm[j], pl[j]);
    qh = make_uint4(ph[0], ph[1], ph[2], ph[3]);
    qm = make_uint4(pm[0], pm[1], pm[2], pm[3]);
    ql = make_uint4(pl[0], pl[1], pl[2], pl[3]);
}

// ---------------- split-bf16 MFMA GEMM: C[M,N] = A[M,K] @ B[K,N] ----------------
template <int IND, int EPI>
__global__ __launch_bounds__(256) void k_gemm_s6(const float* __restrict__ A,
                                                 const float* __restrict__ B0,
                                                 const float* __restrict__ B1,
                                                 const float* __restrict__ B2,
                                                 float* __restrict__ C,
                                                 const int* __restrict__ offs,
                                                 const int* __restrict__ rows,
                                                 const float* __restrict__ rwgt,
                                                 float* __restrict__ hout,
                                                 int Mtot, int N, int K,
                                                 long bStrideZ, long cStrideZ) {
    int z = blockIdx.z;
    int ms, me;
    if (offs) { ms = offs[z]; me = offs[z + 1]; }
    else      { ms = 0; me = Mtot; }
    int p0 = ms + blockIdx.y * 128;
    if (p0 >= me) return;
    const float* Bz;
    if (B1) Bz = (z == 0) ? B0 : (z == 1) ? B1 : B2;
    else    Bz = B0 + (long)z * bStrideZ;
    float* Cz = C ? (C + (long)z * cStrideZ) : nullptr;
    int n0 = blockIdx.x * 128;

    __shared__ __align__(16) unsigned short As[3][128][40];  // planes h/m/l, [m][k]
    __shared__ __align__(16) unsigned short Bs[3][128][40];  // planes h/m/l, [n][k]

    int t = threadIdx.x;
    int lane = t & 63, wave = t >> 6;
    int wm = (wave >> 1) * 64, wn = (wave & 1) * 64;
    int ln = lane & 15, lq = lane >> 4;

    f32x4 acc[4][4];
    f32x4 zero4 = {0.f, 0.f, 0.f, 0.f};
#pragma unroll
    for (int r = 0; r < 4; r++)
#pragma unroll
        for (int c = 0; c < 4; c++) acc[r][c] = zero4;

    int arow = t >> 1, ak0 = (t & 1) * 16;   // A: row, k-half of 32
    const float* aptr = nullptr;
    {
        int pA = p0 + arow;
        if (pA < me) {
            int srow = IND ? rows[pA] : pA;
            aptr = A + (long)srow * K + ak0;
        }
    }
    int brow = t >> 1, bk0 = (t & 1) * 16;
    const float* bbase = Bz + (n0 + brow);

    for (int k0 = 0; k0 < K; k0 += 32) {
        float va[16];
        if (aptr) {
#pragma unroll
            for (int c4 = 0; c4 < 4; c4++) {
                float4 f = *(const float4*)(aptr + k0 + c4 * 4);
                va[c4 * 4 + 0] = f.x; va[c4 * 4 + 1] = f.y;
                va[c4 * 4 + 2] = f.z; va[c4 * 4 + 3] = f.w;
            }
        } else {
#pragma unroll
            for (int j = 0; j < 16; j++) va[j] = 0.f;
        }
        uint4 ah0, am0, al0, ah1, am1, al1;
        split8(va,     ah0, am0, al0);
        split8(va + 8, ah1, am1, al1);
        float vb[16];
        {
            const float* bp = bbase + (long)(k0 + bk0) * N;
#pragma unroll
            for (int j = 0; j < 16; j++) vb[j] = bp[(long)j * N];
        }
        uint4 bh0, bm0, bl0, bh1, bm1, bl1;
        split8(vb,     bh0, bm0, bl0);
        split8(vb + 8, bh1, bm1, bl1);

        __syncthreads();
        *(uint4*)&As[0][arow][ak0]     = ah0;
        *(uint4*)&As[0][arow][ak0 + 8] = ah1;
        *(uint4*)&As[1][arow][ak0]     = am0;
        *(uint4*)&As[1][arow][ak0 + 8] = am1;
        *(uint4*)&As[2][arow][ak0]     = al0;
        *(uint4*)&As[2][arow][ak0 + 8] = al1;
        *(uint4*)&Bs[0][brow][bk0]     = bh0;
        *(uint4*)&Bs[0][brow][bk0 + 8] = bh1;
        *(uint4*)&Bs[1][brow][bk0]     = bm0;
        *(uint4*)&Bs[1][brow][bk0 + 8] = bm1;
        *(uint4*)&Bs[2][brow][bk0]     = bl0;
        *(uint4*)&Bs[2][brow][bk0 + 8] = bl1;
        __syncthreads();

        short8 fah[4], fam[4], fal[4];
#pragma unroll
        for (int r = 0; r < 4; r++) {
            fah[r] = *(const short8*)&As[0][wm + 16 * r + ln][lq * 8];
            fam[r] = *(const short8*)&As[1][wm + 16 * r + ln][lq * 8];
            fal[r] = *(const short8*)&As[2][wm + 16 * r + ln][lq * 8];
        }
#pragma unroll
        for (int c = 0; c < 4; c++) {
            short8 fbh = *(const short8*)&Bs[0][wn + 16 * c + ln][lq * 8];
            short8 fbm = *(const short8*)&Bs[1][wn + 16 * c + ln][lq * 8];
            short8 fbl = *(const short8*)&Bs[2][wn + 16 * c + ln][lq * 8];
#pragma unroll
            for (int r = 0; r < 4; r++) {
                f32x4 a2 = acc[r][c];
                a2 = __builtin_amdgcn_mfma_f32_16x16x32_bf16(fah[r], fbh, a2, 0, 0, 0);
                a2 = __builtin_amdgcn_mfma_f32_16x16x32_bf16(fah[r], fbm, a2, 0, 0, 0);
                a2 = __builtin_amdgcn_mfma_f32_16x16x32_bf16(fam[r], fbh, a2, 0, 0, 0);
                a2 = __builtin_amdgcn_mfma_f32_16x16x32_bf16(fah[r], fbl, a2, 0, 0, 0);
                a2 = __builtin_amdgcn_mfma_f32_16x16x32_bf16(fam[r], fbm, a2, 0, 0, 0);
                a2 = __builtin_amdgcn_mfma_f32_16x16x32_bf16(fal[r], fbh, a2, 0, 0, 0);
                acc[r][c] = a2;
            }
        }
    }

    // C/D: col=lane&15, row=(lane>>4)*4+i  [m89-verified]
#pragma unroll
    for (int r = 0; r < 4; r++)
#pragma unroll
        for (int c = 0; c < 4; c++) {
            int rowb = wm + 16 * r + lq * 4;
            int col  = n0 + wn + 16 * c + ln;
#pragma unroll
            for (int i = 0; i < 4; i++) {
                int p = p0 + rowb + i;
                if (p >= me) continue;
                if (EPI == 2) {
                    atomicAdd(hout + (long)rows[p] * N + col, rwgt[p] * acc[r][c][i]);
                } else if (EPI == 1) {
                    float* cp = Cz + (long)p * N + col;
                    *cp += acc[r][c][i];
                } else {
                    Cz[(long)p * N + col] = acc[r][c][i];
                }
            }
        }
}

// ---------------- split-bf16 MFMA flash attention ----------------
// Block: 256 thr = 4 waves; 64 Q-rows per block (wave w owns rows 16w..16w+15),
// K/V tiles of 64. Q A-frags pre-split in registers. K staged [kv][d] bf16 x3
// planes (natural QK^T B-operand). V staged TRANSPOSED [d][kv] bf16 x3 planes
// via row-contiguous ds_write_b16 (natural PV B-operand). P fp32 in LDS,
// band-local (no cross-wave softmax, no extra barrier), split on the fly for
// the PV A-frag. 6 MFMAs per fp32 MAC (exact 3-plane) -> rel err ~1e-7.
__global__ __launch_bounds__(256) void k_attn_mfma(const float* __restrict__ q,
                                                   const float* __restrict__ k,
                                                   const float* __restrict__ v,
                                                   float* __restrict__ o) {
    int head = blockIdx.y;
    // pair long/short q-tiles across co-resident blocks (causal balance)
    int qi = ((blockIdx.y >> 3) & 1) ? (int)(gridDim.x - 1 - blockIdx.x) : (int)blockIdx.x;
    int q0 = qi * 64;

    __shared__ __align__(16) unsigned short Ks[3][64][72];  // [plane][kv][d]
    __shared__ __align__(16) unsigned short Vt[3][64][72];  // [plane][d][kv]
    __shared__ __align__(16) float Ps[64][68];              // [q][kv] fp32

    int t = threadIdx.x;
    int lane = t & 63, w = t >> 6;
    int ln = lane & 15, lq = lane >> 4;

    // --- Q frags: load + split once, held in registers ---
    short8 qh[2], qm[2], qlr[2];
    {
        const float* qp = q + ((long)(q0 + 16 * w + ln) * H_ + head) * HD_;
#pragma unroll
        for (int ks = 0; ks < 2; ks++) {
            float vq[8];
            float4 f0 = *(const float4*)(qp + 32 * ks + lq * 8);
            float4 f1 = *(const float4*)(qp + 32 * ks + lq * 8 + 4);
            vq[0] = f0.x; vq[1] = f0.y; vq[2] = f0.z; vq[3] = f0.w;
            vq[4] = f1.x; vq[5] = f1.y; vq[6] = f1.z; vq[7] = f1.w;
            uint4 hh, mm, ll;
            split8(vq, hh, mm, ll);
            qh[ks] = u2s8(hh); qm[ks] = u2s8(mm); qlr[ks] = u2s8(ll);
        }
    }

    f32x4 oc[4];
    f32x4 zero4 = {0.f, 0.f, 0.f, 0.f};
#pragma unroll
    for (int c = 0; c < 4; c++) oc[c] = zero4;
    float m_run[4], l_run[4];
#pragma unroll
    for (int i = 0; i < 4; i++) { m_run[i] = -3.402823466e38f; l_run[i] = 0.f; }

    for (int kt = 0; kt <= qi; kt++) {
        __syncthreads();
        {
            // K stage: thread -> row t>>2, d-quarter t&3 (b128 plane writes)
            int kr = t >> 2, kq4 = (t & 3) * 16;
            const float* kp = k + ((long)(kt * 64 + kr) * H_ + head) * HD_ + kq4;
            float vk[16];
#pragma unroll
            for (int j = 0; j < 4; j++) {
                float4 f = *(const float4*)(kp + 4 * j);
                vk[4 * j + 0] = f.x; vk[4 * j + 1] = f.y;
                vk[4 * j + 2] = f.z; vk[4 * j + 3] = f.w;
            }
            uint4 h0, m0, l0, h1, m1, l1;
            split8(vk,     h0, m0, l0);
            split8(vk + 8, h1, m1, l1);
            *(uint4*)&Ks[0][kr][kq4]     = h0; *(uint4*)&Ks[0][kr][kq4 + 8] = h1;
            *(uint4*)&Ks[1][kr][kq4]     = m0; *(uint4*)&Ks[1][kr][kq4 + 8] = m1;
            *(uint4*)&Ks[2][kr][kq4]     = l0; *(uint4*)&Ks[2][kr][kq4 + 8] = l1;
            // V stage transposed: thread -> kv=lane, d-block w*16 (row-contig b16)
            const float* vp = v + ((long)(kt * 64 + lane) * H_ + head) * HD_ + w * 16;
            float vvv[16];
#pragma unroll
            for (int j = 0; j < 4; j++) {
                float4 f = *(const float4*)(vp + 4 * j);
                vvv[4 * j + 0] = f.x; vvv[4 * j + 1] = f.y;
                vvv[4 * j + 2] = f.z; vvv[4 * j + 3] = f.w;
            }
#pragma unroll
            for (int j = 0; j < 16; j++) {
                float x = vvv[j];
                unsigned uu = __float_as_uint(x);
                unsigned hh = uu & 0xFFFF0000u;
                float rr = x - __uint_as_float(hh);
                unsigned mm2 = __float_as_uint(rr) & 0xFFFF0000u;
                float ss2 = rr - __uint_as_float(mm2);
                Vt[0][w * 16 + j][lane] = (unsigned short)(hh >> 16);
                Vt[1][w * 16 + j][lane] = (unsigned short)(mm2 >> 16);
                Vt[2][w * 16 + j][lane] = (unsigned short)(__float_as_uint(ss2) >> 16);
            }
        }
        __syncthreads();

        // ---- QK^T: S[16w + 4lq + i][16c + ln]
        f32x4 sc[4];
#pragma unroll
        for (int c = 0; c < 4; c++) sc[c] = zero4;
#pragma unroll
        for (int ks = 0; ks < 2; ks++) {
#pragma unroll
            for (int c = 0; c < 4; c++) {
                const int co = 16 * c + ln, ko = 32 * ks + lq * 8;
                short8 bh = *(const short8*)&Ks[0][co][ko];
                short8 bm = *(const short8*)&Ks[1][co][ko];
                short8 bl = *(const short8*)&Ks[2][co][ko];
                f32x4 a2 = sc[c];
                a2 = __builtin_amdgcn_mfma_f32_16x16x32_bf16(qh[ks],  bh, a2, 0, 0, 0);
                a2 = __builtin_amdgcn_mfma_f32_16x16x32_bf16(qh[ks],  bm, a2, 0, 0, 0);
                a2 = __builtin_amdgcn_mfma_f32_16x16x32_bf16(qm[ks],  bh, a2, 0, 0, 0);
                a2 = __builtin_amdgcn_mfma_f32_16x16x32_bf16(qh[ks],  bl, a2, 0, 0, 0);
                a2 = __builtin_amdgcn_mfma_f32_16x16x32_bf16(qm[ks],  bm, a2, 0, 0, 0);
                a2 = __builtin_amdgcn_mfma_f32_16x16x32_bf16(qlr[ks], bh, a2, 0, 0, 0);
                sc[c] = a2;
            }
        }

        // ---- online softmax (rows 16w+4lq+i, band-local, shfl over ln lanes)
#pragma unroll
        for (int i = 0; i < 4; i++) {
            int qg = q0 + 16 * w + 4 * lq + i;
            float mx = -3.402823466e38f;
#pragma unroll
            for (int c = 0; c < 4; c++) {
                int kvg = kt * 64 + 16 * c + ln;
                float s = sc[c][i] * 0.125f;
                s = (kvg <= qg) ? s : -3.402823466e38f;
                sc[c][i] = s;
                mx = fmaxf(mx, s);
            }
            mx = fmaxf(mx, __shfl_xor(mx, 1));
            mx = fmaxf(mx, __shfl_xor(mx, 2));
            mx = fmaxf(mx, __shfl_xor(mx, 4));
            mx = fmaxf(mx, __shfl_xor(mx, 8));
            float mn = fmaxf(m_run[i], mx);
            float al = expf(m_run[i] - mn);
            m_run[i] = mn;
            float sum = 0.f;
#pragma unroll
            for (int c = 0; c < 4; c++) {
                float e = expf(sc[c][i] - mn);
                Ps[16 * w + 4 * lq + i][16 * c + ln] = e;
                sum += e;
            }
            sum += __shfl_xor(sum, 1);
            sum += __shfl_xor(sum, 2);
            sum += __shfl_xor(sum, 4);
            sum += __shfl_xor(sum, 8);
            l_run[i] = l_run[i] * al + sum;
#pragma unroll
            for (int c = 0; c < 4; c++) oc[c][i] *= al;
        }

        // ---- PV: O[16w + 4lq + i][16c + ln] += P @ V
        // (Ps written/read within the same wave band -> lockstep + lgkmcnt, no barrier)
#pragma unroll
        for (int ks = 0; ks < 2; ks++) {
            float pv8[8];
            *(float4*)&pv8[0] = *(const float4*)&Ps[16 * w + ln][32 * ks + lq * 8];
            *(float4*)&pv8[4] = *(const float4*)&Ps[16 * w + ln][32 * ks + lq * 8 + 4];
            uint4 ph4, pm4, pl4;
            split8(pv8, ph4, pm4, pl4);
            short8 pah = u2s8(ph4), pam = u2s8(pm4), pal = u2s8(pl4);
#pragma unroll
            for (int c = 0; c < 4; c++) {
                const int co = 16 * c + ln, ko = 32 * ks + lq * 8;
                short8 bh = *(const short8*)&Vt[0][co][ko];
                short8 bm = *(const short8*)&Vt[1][co][ko];
                short8 bl = *(const short8*)&Vt[2][co][ko];
                f32x4 a2 = oc[c];
                a2 = __builtin_amdgcn_mfma_f32_16x16x32_bf16(pah, bh, a2, 0, 0, 0);
                a2 = __builtin_amdgcn_mfma_f32_16x16x32_bf16(pah, bm, a2, 0, 0, 0);
                a2 = __builtin_amdgcn_mfma_f32_16x16x32_bf16(pam, bh, a2, 0, 0, 0);
                a2 = __builtin_amdgcn_mfma_f32_16x16x32_bf16(pah, bl, a2, 0, 0, 0);
                a2 = __builtin_amdgcn_mfma_f32_16x16x32_bf16(pam, bm, a2, 0, 0, 0);
                a2 = __builtin_amdgcn_mfma_f32_16x16x32_bf16(pal, bh, a2, 0, 0, 0);
                oc[c] = a2;
            }
        }
    }

    // ---- epilogue: O /= l, store
#pragma unroll
    for (int i = 0; i < 4; i++) {
        float invl = 1.0f / l_run[i];
        int qg = q0 + 16 * w + 4 * lq + i;
        float* op = o + ((long)qg * H_ + head) * HD_;
#pragma unroll
        for (int c = 0; c < 4; c++) op[16 * c + ln] = oc[c][i] * invl;
    }
}

// ---------------- router: gate logits, softmax-top2 (stable), counts --------
__global__ __launch_bounds__(256) void k_router(const float* __restrict__ x,
                                                const float* __restrict__ gw,
                                                int* __restrict__ idx, float* __restrict__ wgt,
                                                int* __restrict__ cnt) {
    int tok  = (blockIdx.x << 2) | (threadIdx.x >> 6);
    int lane = threadIdx.x & 63;
    float acc[8] = {0.f, 0.f, 0.f, 0.f, 0.f, 0.f, 0.f, 0.f};
    for (int i = 0; i < 16; i++) {
        int d = lane + i * 64;
        float xv = x[(long)tok * D_ + d];
        const float* gp = gw + (long)d * E_;
#pragma unroll
        for (int e = 0; e < 8; e++) acc[e] = fmaf(xv, gp[e], acc[e]);
    }
#pragma unroll
    for (int e = 0; e < 8; e++)
#pragma unroll
        for (int m = 32; m >= 1; m >>= 1) acc[e] += __shfl_xor(acc[e], m);
    if (lane == 0) {
        int i1 = 0; float m1 = acc[0];
        for (int e = 1; e < 8; e++) if (acc[e] > m1) { m1 = acc[e]; i1 = e; }
        int i2 = -1; float m2 = -3.402823466e38f;
        for (int e = 0; e < 8; e++) if (e != i1 && acc[e] > m2) { m2 = acc[e]; i2 = e; }
        float w1 = 1.0f / (1.0f + expf(m2 - m1));
        idx[tok * 2] = i1; idx[tok * 2 + 1] = i2;
        wgt[tok * 2] = w1; wgt[tok * 2 + 1] = 1.0f - w1;
        atomicAdd(&cnt[i1], 1);
        atomicAdd(&cnt[i2], 1);
    }
}

__global__ void k_offsets(const int* __restrict__ cnt, int* __restrict__ off) {
    if (threadIdx.x == 0) {
        int run = 0;
        for (int e = 0; e < 8; e++) { off[e] = run; run += cnt[e]; }
        off[8] = run;
    }
}

__global__ __launch_bounds__(256) void k_scatter(const int* __restrict__ idx,
                                                 const float* __restrict__ wgt,
                                                 const int* __restrict__ off,
                                                 int* __restrict__ fill,
                                                 int* __restrict__ rows,
                                                 float* __restrict__ rwgt) {
    int tok = blockIdx.x * 256 + threadIdx.x;
#pragma unroll
    for (int j = 0; j < 2; j++) {
        int e = idx[tok * 2 + j];
        int pos = off[e] + atomicAdd(&fill[e], 1);
        rows[pos] = tok;
        rwgt[pos] = wgt[tok * 2 + j];
    }
}

__global__ __launch_bounds__(256) void k_silumul(const float* __restrict__ g,
                                                 const float* __restrict__ u,
                                                 float* __restrict__ z) {
    long i = (long)(blockIdx.x * 256 + threadIdx.x) * 4;
    float4 gv = *(const float4*)(g + i);
    float4 uv = *(const float4*)(u + i);
    float4 zv;
    zv.x = gv.x / (1.f + expf(-gv.x)) * uv.x;
    zv.y = gv.y / (1.f + expf(-gv.y)) * uv.y;
    zv.z = gv.z / (1.f + expf(-gv.z)) * uv.z;
    zv.w = gv.w / (1.f + expf(-gv.w)) * uv.w;
    *(float4*)(z + i) = zv;
}

// ---------------- transpose + cast: out_w (1024,32000) f32 -> (32000,1024) bf16
__global__ __launch_bounds__(256) void k_transcast(const float* __restrict__ in,
                                                   unsigned short* __restrict__ out) {
    int c0 = blockIdx.x * 32;   // n
    int r0 = blockIdx.y * 32;   // k
    __shared__ __align__(16) float T[32][36];
    int t = threadIdx.x;
    {
        int row = t >> 3, cq = (t & 7) * 4;
        *(float4*)&T[row][cq] = *(const float4*)(in + (long)(r0 + row) * V_ + c0 + cq);
    }
    __syncthreads();
    {
        int n = t >> 3, kq = (t & 7) * 4;
        ushort4 u;
        u.x = f2bf(T[kq + 0][n]); u.y = f2bf(T[kq + 1][n]);
        u.z = f2bf(T[kq + 2][n]); u.w = f2bf(T[kq + 3][n]);
        *(ushort4*)(out + (long)(c0 + n) * D_ + r0 + kq) = u;
    }
}

// ---------------- bf16 MFMA GEMM for logits: C = A(2048,1024) @ BT(32000,1024)^T
__global__ __launch_bounds__(256) void k_gemm_bf16(const unsigned short* __restrict__ A,
                                                   const unsigned short* __restrict__ BT,
                                                   float* __restrict__ C) {
    int m0 = blockIdx.x * 128, n0 = blockIdx.y * 128;
    __shared__ __align__(16) unsigned short As[128][40];
    __shared__ __align__(16) unsigned short Bs[128][40];
    int t = threadIdx.x;
    int lane = t & 63, wave = t >> 6;
    int wm = (wave >> 1) * 64, wn = (wave & 1) * 64;
    int ln = lane & 15, lq = lane >> 4;
    f32x4 acc[4][4];
    f32x4 zero4 = {0.f, 0.f, 0.f, 0.f};
#pragma unroll
    for (int r = 0; r < 4; r++)
#pragma unroll
        for (int c = 0; c < 4; c++) acc[r][c] = zero4;
    int rowA = t >> 1;
    int q1 = (t * 2) & 3, q2 = (t * 2 + 1) & 3;
    for (int k0 = 0; k0 < 1024; k0 += 32) {
        const uint4* ap = (const uint4*)(A + (long)(m0 + rowA) * 1024 + k0);
        const uint4* bp = (const uint4*)(BT + (long)(n0 + rowA) * 1024 + k0);
        uint4 a0 = ap[q1], a1 = ap[q2];
        uint4 b0 = bp[q1], b1 = bp[q2];
        __syncthreads();
        *(uint4*)&As[rowA][q1 * 8] = a0;
        *(uint4*)&As[rowA][q2 * 8] = a1;
        *(uint4*)&Bs[rowA][q1 * 8] = b0;
        *(uint4*)&Bs[rowA][q2 * 8] = b1;
        __syncthreads();
        short8 a[4], b[4];
#pragma unroll
        for (int r = 0; r < 4; r++) a[r] = *(const short8*)&As[wm + 16 * r + ln][lq * 8];
#pragma unroll
        for (int c = 0; c < 4; c++) b[c] = *(const short8*)&Bs[wn + 16 * c + ln][lq * 8];
#pragma unroll
        for (int r = 0; r < 4; r++)
#pragma unroll
            for (int c = 0; c < 4; c++)
                acc[r][c] = __builtin_amdgcn_mfma_f32_16x16x32_bf16(a[r], b[c], acc[r][c], 0, 0, 0);
    }
#pragma unroll
    for (int r = 0; r < 4; r++)
#pragma unroll
        for (int c = 0; c < 4; c++) {
            int row = m0 + wm + 16 * r + lq * 4;
            int col = n0 + wn + 16 * c + ln;
#pragma unroll
            for (int i = 0; i < 4; i++)
                C[(long)(row + i) * V_ + col] = acc[r][c][i];
        }
}

// ---------------- host ----------------
extern "C" void kernel_launch(void* const* d_in, const int* in_sizes, int n_in,
                              void* d_out, int out_size, void* d_ws, size_t ws_size,
                              hipStream_t stream) {
    (void)in_sizes; (void)n_in; (void)out_size; (void)ws_size;
    const int*   ids   = (const int*)d_in[0];
    const float* embed = (const float*)d_in[1];
    const float* wq    = (const float*)d_in[2];
    const float* wk    = (const float*)d_in[3];
    const float* wv    = (const float*)d_in[4];
    const float* wo    = (const float*)d_in[5];
    const float* qnw   = (const float*)d_in[6];
    const float* knw   = (const float*)d_in[7];
    const float* anw   = (const float*)d_in[8];
    const float* fnw   = (const float*)d_in[9];
    const float* gatew = (const float*)d_in[10];
    const float* wgate = (const float*)d_in[11];
    const float* wup   = (const float*)d_in[12];
    const float* wdown = (const float*)d_in[13];
    const float* finw  = (const float*)d_in[14];
    const float* outw  = (const float*)d_in[15];
    const float* cosb  = (const float*)d_in[16];
    const float* sinb  = (const float*)d_in[17];
    float* out = (float*)d_out;

    char* w = (char*)d_ws;
    float* h  = (float*)(w);
    float* x  = (float*)(w + 8388608);
    float* q  = (float*)(w + 16777216);
    float* kk = (float*)(w + 25165824);
    float* vv = (float*)(w + 33554432);
    float* ao = (float*)(w + 41943040);
    float* g  = (float*)(w + 50331648);
    float* u  = (float*)(w + 62914560);
    float* z  = (float*)(w + 75497472);
    unsigned short* hn  = (unsigned short*)(w + 88080384);
    unsigned short* owT = (unsigned short*)(w + 16777216);  // overlays q..z (dead by then)
    char* rbase = w + 92274688;
    int*   idx  = (int*)(rbase);
    float* wgt  = (float*)(rbase + 16384);
    int*   cnt  = (int*)(rbase + 32768);
    int*   fill = (int*)(rbase + 32768 + 32);
    int*   offs = (int*)(rbase + 32768 + 64);
    int*   rows = (int*)(rbase + 32768 + 128);
    float* rwgt = (float*)(rbase + 32768 + 128 + 16384);

    k_gather<<<2048, 256, 0, stream>>>(ids, embed, h);

    for (int l = 0; l < 2; l++) {
        const float* wq_l = wq + (long)l * D_ * D_;
        const float* wk_l = wk + (long)l * D_ * D_;
        const float* wv_l = wv + (long)l * D_ * D_;
        const float* wo_l = wo + (long)l * D_ * D_;
        const float* an_l = anw + l * D_;
        const float* fn_l = fnw + l * D_;
        const float* qn_l = qnw + l * HD_;
        const float* kn_l = knw + l * HD_;
        const float* gw_l = gatew + (long)l * D_ * E_;
        const float* wg_l = wgate + (long)l * E_ * D_ * MF_;
        const float* wu_l = wup   + (long)l * E_ * D_ * MF_;
        const float* wd_l = wdown + (long)l * E_ * MF_ * D_;

        k_rmsnorm<0><<<2048, 256, 0, stream>>>(h, an_l, x, nullptr);
        k_gemm_s6<0, 0><<<dim3(8, 16, 3), 256, 0, stream>>>(x, wq_l, wk_l, wv_l, q,
            nullptr, nullptr, nullptr, nullptr, 2048, 1024, 1024, 0, 2048L * 1024);
        k_qkrope<<<16384, 256, 0, stream>>>(q, kk, qn_l, kn_l, cosb, sinb);
        k_attn_mfma<<<dim3(32, 16), 256, 0, stream>>>(q, kk, vv, ao);
        k_gemm_s6<0, 1><<<dim3(8, 16, 1), 256, 0, stream>>>(ao, wo_l, nullptr, nullptr, h,
            nullptr, nullptr, nullptr, nullptr, 2048, 1024, 1024, 0, 0);
        k_rmsnorm<0><<<2048, 256, 0, stream>>>(h, fn_l, x, nullptr);
        hipMemsetAsync(cnt, 0, 64, stream);
        k_router<<<512, 256, 0, stream>>>(x, gw_l, idx, wgt, cnt);
        k_offsets<<<1, 64, 0, stream>>>(cnt, offs);
        k_scatter<<<8, 256, 0, stream>>>(idx, wgt, offs, fill, rows, rwgt);
        k_gemm_s6<1, 0><<<dim3(6, 16, 8), 256, 0, stream>>>(x, wg_l, nullptr, nullptr, g,
            offs, rows, nullptr, nullptr, 4096, 768, 1024, (long)D_ * MF_, 0);
        k_gemm_s6<1, 0><<<dim3(6, 16, 8), 256, 0, stream>>>(x, wu_l, nullptr, nullptr, u,
            offs, rows, nullptr, nullptr, 4096, 768, 1024, (long)D_ * MF_, 0);
        k_silumul<<<3072, 256, 0, stream>>>(g, u, z);
        k_gemm_s6<0, 2><<<dim3(8, 16, 8), 256, 0, stream>>>(z, wd_l, nullptr, nullptr, nullptr,
            offs, rows, rwgt, h, 4096, 1024, 768, (long)MF_ * D_, 0);
    }

    k_rmsnorm<1><<<2048, 256, 0, stream>>>(h, finw, nullptr, hn);
    k_transcast<<<dim3(1000, 32), 256, 0, stream>>>(outw, owT);
    k_gemm_bf16<<<dim3(16, 250), 256, 0, stream>>>(hn, owT, out);
}